// Round 1
// baseline (674.603 us; speedup 1.0000x reference)
//
#include <hip/hip_runtime.h>
#include <hip/hip_bf16.h>
#include <stdint.h>

// BitLinear: out = LayerNorm(x) @ sign(W - mean(W))^T * mean|W - mean(W)|
// M=8192 (B*S), K=4096 (D_in), N=4096 (D_out). fp32 in/out, bf16 MFMA GEMM.

typedef __bf16 bf16x8 __attribute__((ext_vector_type(8)));
typedef float f32x4 __attribute__((ext_vector_type(4)));

#define BM 128
#define BN 128
#define BK 32

// ---------- helpers ----------

__device__ __forceinline__ void gl_lds16(const void* g, void* l) {
  // async global->LDS, 16B/lane; LDS dest is wave-uniform base + lane*16
  __builtin_amdgcn_global_load_lds(
      (const __attribute__((address_space(1))) void*)g,
      (__attribute__((address_space(3))) void*)l,
      16, 0, 0);
}

__device__ __forceinline__ unsigned short f2bf_rne(float f) {
  unsigned int u = __float_as_uint(f);
  unsigned int r = (u + 0x7FFFu + ((u >> 16) & 1u)) >> 16;
  return (unsigned short)r;
}

__device__ __forceinline__ float wave_red(float v) {
#pragma unroll
  for (int o = 32; o > 0; o >>= 1) v += __shfl_down(v, o, 64);
  return v;
}

// valid on threadIdx.x==0 only
__device__ __forceinline__ float block_red(float v) {
  __shared__ float tmp[4];
  const int wave = threadIdx.x >> 6, lane = threadIdx.x & 63;
  v = wave_red(v);
  if (lane == 0) tmp[wave] = v;
  __syncthreads();
  float r = 0.f;
  if (threadIdx.x == 0) r = tmp[0] + tmp[1] + tmp[2] + tmp[3];
  return r;
}

// ---------- kernels ----------

__global__ void zero_kernel(float* p) {
  if (threadIdx.x < 8) p[threadIdx.x] = 0.f;
}

// sum(W) -> scal[0]
__global__ __launch_bounds__(256) void wsum_kernel(const float* __restrict__ w,
                                                   float* __restrict__ scal, int n4) {
  int idx = blockIdx.x * 256 + threadIdx.x;
  int stride = gridDim.x * 256;
  const float4* w4 = (const float4*)w;
  float s = 0.f;
  for (int i = idx; i < n4; i += stride) {
    float4 a = w4[i];
    s += a.x + a.y + a.z + a.w;
  }
  float tot = block_red(s);
  if (threadIdx.x == 0) atomicAdd(&scal[0], tot);
}

// w_bin = sign(W - mean) as bf16 bits; sum|W - mean| -> scal[1]
__global__ __launch_bounds__(256) void wbin_kernel(const float* __restrict__ w,
                                                   float* __restrict__ scal,
                                                   unsigned short* __restrict__ wb,
                                                   int n4, float inv_n) {
  const float mean = scal[0] * inv_n;
  int idx = blockIdx.x * 256 + threadIdx.x;
  int stride = gridDim.x * 256;
  const float4* w4 = (const float4*)w;
  ushort4* wb4 = (ushort4*)wb;
  float sa = 0.f;
  for (int i = idx; i < n4; i += stride) {
    float4 a = w4[i];
    float dx = a.x - mean, dy = a.y - mean, dz = a.z - mean, dw = a.w - mean;
    sa += fabsf(dx) + fabsf(dy) + fabsf(dz) + fabsf(dw);
    ushort4 o;
    o.x = dx > 0.f ? 0x3F80u : (dx < 0.f ? 0xBF80u : 0u);
    o.y = dy > 0.f ? 0x3F80u : (dy < 0.f ? 0xBF80u : 0u);
    o.z = dz > 0.f ? 0x3F80u : (dz < 0.f ? 0xBF80u : 0u);
    o.w = dw > 0.f ? 0x3F80u : (dw < 0.f ? 0xBF80u : 0u);
    wb4[i] = o;
  }
  float tot = block_red(sa);
  if (threadIdx.x == 0) atomicAdd(&scal[1], tot);
}

// LayerNorm over last dim (D=4096), output bf16. One block per row.
__global__ __launch_bounds__(256) void ln_kernel(const float* __restrict__ x,
                                                 __bf16* __restrict__ xn) {
  const int row = blockIdx.x;
  const float4* xr = (const float4*)(x + (size_t)row * 4096);
  const int tid = threadIdx.x;
  float4 v[4];
  float s = 0.f, ss = 0.f;
#pragma unroll
  for (int t = 0; t < 4; t++) {
    float4 a = xr[t * 256 + tid];
    v[t] = a;
    s += a.x + a.y + a.z + a.w;
    ss += a.x * a.x + a.y * a.y + a.z * a.z + a.w * a.w;
  }
#pragma unroll
  for (int o = 32; o > 0; o >>= 1) {
    s += __shfl_down(s, o, 64);
    ss += __shfl_down(ss, o, 64);
  }
  __shared__ float rs[8];
  const int wave = tid >> 6, lane = tid & 63;
  if (lane == 0) { rs[wave] = s; rs[4 + wave] = ss; }
  __syncthreads();
  s = rs[0] + rs[1] + rs[2] + rs[3];
  ss = rs[4] + rs[5] + rs[6] + rs[7];
  const float mu = s * (1.0f / 4096.0f);
  const float var = ss * (1.0f / 4096.0f) - mu * mu;  // jnp.var: population
  const float rstd = rsqrtf(var + 1e-5f);
  ushort4* xw = (ushort4*)((unsigned short*)xn + (size_t)row * 4096);
#pragma unroll
  for (int t = 0; t < 4; t++) {
    float4 a = v[t];
    ushort4 o;
    o.x = f2bf_rne((a.x - mu) * rstd);
    o.y = f2bf_rne((a.y - mu) * rstd);
    o.z = f2bf_rne((a.z - mu) * rstd);
    o.w = f2bf_rne((a.w - mu) * rstd);
    xw[t * 256 + tid] = o;
  }
}

// C[M,N] = A[M,K] * B[N,K]^T * beta   (m97 structure: 128x128 tile, BK=32,
// 4 waves of 4x4 16x16x32 bf16 MFMA, global_load_lds width=16)
__global__ __launch_bounds__(256) void gemm_kernel(const __bf16* __restrict__ A,
                                                   const __bf16* __restrict__ Bm,
                                                   float* __restrict__ C,
                                                   const float* __restrict__ scal,
                                                   float beta_scale,
                                                   int M, int N, int K) {
  __shared__ __align__(16) __bf16 sA[BM * BK];  // row-major 128x32, no pad (gl_lds)
  __shared__ __align__(16) __bf16 sB[BN * BK];

  const int tid = threadIdx.x;
  const int wave = tid >> 6;
  const int lane = tid & 63;

  const int rowBase = blockIdx.x * BM;
  const int colBase = blockIdx.y * BN;

  const float beta = scal[1] * beta_scale;

  // staging: lane covers row (lane/4) of a 16-row chunk, 8 bf16 at col (lane%4)*8
  const int sRow = lane >> 2;
  const int sCol = (lane & 3) << 3;
  const __bf16* gA = A + (size_t)(rowBase + sRow) * K + sCol;
  const __bf16* gB = Bm + (size_t)(colBase + sRow) * K + sCol;
  const int c0 = wave * 2, c1 = wave * 2 + 1;  // two 16-row chunks per wave

  // fragment addressing (16x16x32): m/n = lane&15, k = (lane>>4)*8 + j
  const int wm = (wave >> 1) << 6;  // wave's 64x64 quadrant
  const int wn = (wave & 1) << 6;
  const int fr = lane & 15;
  const int fk = (lane >> 4) << 3;

  f32x4 acc[4][4];
#pragma unroll
  for (int i = 0; i < 4; i++)
#pragma unroll
    for (int j = 0; j < 4; j++) acc[i][j] = (f32x4){0.f, 0.f, 0.f, 0.f};

  for (int kt = 0; kt < K; kt += BK) {
    gl_lds16(gA + (size_t)c0 * 16 * K + kt, &sA[c0 * 512]);
    gl_lds16(gA + (size_t)c1 * 16 * K + kt, &sA[c1 * 512]);
    gl_lds16(gB + (size_t)c0 * 16 * K + kt, &sB[c0 * 512]);
    gl_lds16(gB + (size_t)c1 * 16 * K + kt, &sB[c1 * 512]);
    __syncthreads();  // drains vmcnt -> staged data visible

    bf16x8 af[4], bf[4];
#pragma unroll
    for (int i = 0; i < 4; i++)
      af[i] = *(const bf16x8*)&sA[(wm + i * 16 + fr) * BK + fk];
#pragma unroll
    for (int j = 0; j < 4; j++)
      bf[j] = *(const bf16x8*)&sB[(wn + j * 16 + fr) * BK + fk];
#pragma unroll
    for (int i = 0; i < 4; i++)
#pragma unroll
      for (int j = 0; j < 4; j++)
        acc[i][j] = __builtin_amdgcn_mfma_f32_16x16x32_bf16(af[i], bf[j], acc[i][j], 0, 0, 0);
    __syncthreads();  // protect LDS before next stage
  }

  // C/D layout: col = lane&15, row = (lane>>4)*4 + reg  [m89/m91 verified]
  const int orow = rowBase + wm + ((lane >> 4) << 2);
  const int ocol = colBase + wn + (lane & 15);
#pragma unroll
  for (int i = 0; i < 4; i++)
#pragma unroll
    for (int j = 0; j < 4; j++)
#pragma unroll
      for (int r = 0; r < 4; r++)
        C[(size_t)(orow + i * 16 + r) * N + (ocol + j * 16)] = acc[i][j][r] * beta;
}

// ---------- launch ----------

extern "C" void kernel_launch(void* const* d_in, const int* in_sizes, int n_in,
                              void* d_out, int out_size, void* d_ws, size_t ws_size,
                              hipStream_t stream) {
  const float* x = (const float*)d_in[0];   // [4,2048,4096] fp32
  const float* w = (const float*)d_in[1];   // [4096,4096] fp32
  float* out = (float*)d_out;               // [4,2048,4096] fp32

  const int K = 4096;
  const int M = in_sizes[0] / K;  // 8192
  const int N = in_sizes[1] / K;  // 4096
  const int nw = N * K;           // 16777216
  const float inv_nw = 1.0f / (float)nw;

  char* ws = (char*)d_ws;
  float* scal = (float*)ws;                                  // [0]=sum(W), [1]=sum|W-mean|
  __bf16* wbin = (__bf16*)(ws + 256);                        // N*K bf16 = 32 MB
  __bf16* xn = (__bf16*)(ws + 256 + (size_t)nw * 2);         // M*K bf16 = 64 MB

  zero_kernel<<<1, 64, 0, stream>>>(scal);
  wsum_kernel<<<1024, 256, 0, stream>>>(w, scal, nw / 4);
  wbin_kernel<<<1024, 256, 0, stream>>>(w, scal, (unsigned short*)wbin, nw / 4, inv_nw);
  ln_kernel<<<M, 256, 0, stream>>>(x, xn);
  dim3 grid(M / BM, N / BN);
  gemm_kernel<<<grid, 256, 0, stream>>>(xn, wbin, out, scal, inv_nw, M, N, K);
}